// Round 8
// baseline (253.498 us; speedup 1.0000x reference)
//
#include <hip/hip_runtime.h>
#include <hip/hip_bf16.h>

// Full attention, B=4 L=S=2048 H=16 E=D=64, fp32 in/out, UNSCALED scores.
// Round 12: RESUBMIT of round 10/11 (two GPU acquisition timeouts; never ran).
// Round-8's two ideas, implemented soundly:
//  (1) T14 async-stage pipeline with PLAIN C loads (compiler owns dataflow,
//      inserts precise vmcnt before first use -> correct by construction),
//      pinned against sinking by __builtin_amdgcn_sched_barrier(0) right
//      after issue (round 5's failure: loads sank to use site). LDS K/V
//      double-buffered; convert+ds_write AFTER compute; ONE barrier/iter.
//      [Round 8/9's asm-volatile loads consumed as plain C were unsound:
//       "memory" clobber doesn't order register dataflow -> absmax inf.]
//  (2) XCD sibling-grouping remap: qt=blk>>6, bh=blk&63 -> all 8 q-tile
//      blocks of one (b,h) share blk%8 (same XCD, assuming round-robin) ->
//      per-tile K/V reuse is L2-local and drift-tolerant (live window
//      ~0.5 MB << 4 MiB L2). Makes (1)'s inter-block drift harmless.
// Arithmetic per q-row bitwise-identical to round 7 (absmax 0.1015625):
// 2-term Q hi/lo split, bf16 K/P/V, fixed-max softmax via exp2(log2e*Q),
// in-register P^T with permuted V^T slot order.

#define BN 64    // S-tile
#define BM 256   // Q-tile per block (32 per wave, 2 qsets of 16)
#define KP 72    // padded LDS row stride (bf16 elems)

typedef __attribute__((ext_vector_type(8))) __bf16 bf16x8;
typedef __attribute__((ext_vector_type(4))) __bf16 bf16x4;
typedef __attribute__((ext_vector_type(4))) float  f32x4;

#if __has_builtin(__builtin_amdgcn_exp2f)
#define EXP2F(x) __builtin_amdgcn_exp2f(x)
#else
#define EXP2F(x) exp2f(x)
#endif

__device__ __forceinline__ f32x4 mfma16(bf16x8 a, bf16x8 b, f32x4 c) {
    return __builtin_amdgcn_mfma_f32_16x16x32_bf16(a, b, c, 0, 0, 0);
}

__global__ __launch_bounds__(512, 4)
void attn_kernel(const float* __restrict__ Qg, const float* __restrict__ Kg,
                 const float* __restrict__ Vg, float* __restrict__ Og)
{
    constexpr int B = 4, L = 2048, S = 2048, H = 16, E = 64, D = 64;
    constexpr int NT = S / BN;
    constexpr float LOG2E = 1.44269504088896f;

    __shared__ __bf16 Khi[2][BN * KP];   // K tile, bf16, [s][e], double-buffered
    __shared__ __bf16 Vt [2][D  * KP];   // V^T [d][slot], permuted slots, dbuf

    const int tid  = threadIdx.x;
    const int lane = tid & 63;
    const int wv   = tid >> 6;          // 0..7
    const int quad = lane >> 4;
    const int l16  = lane & 15;

    // XCD sibling grouping: blk = qt*64 + bh -> the 8 qt-siblings of one bh
    // share blk%8 (same XCD under round-robin) -> K/V tile reuse is L2-local.
    const int blk = blockIdx.x;
    const int qt  = blk >> 6;        // 0..7
    const int bh  = blk & 63;
    const int h   = bh & 15;
    const int b   = bh >> 4;

    const int q0w = qt * BM + wv * 32;   // this wave's first query row (32 rows)

    // ---- Load Q fragments once, scaled by log2(e), hi/lo split (residual in qlo)
    bf16x8 qhi[2][2], qlo[2][2];   // [qset][kk]
    #pragma unroll
    for (int g = 0; g < 2; ++g) {
        const float* qrow = Qg + (((size_t)b * L + q0w + g * 16 + l16) * H + h) * E;
        #pragma unroll
        for (int kk = 0; kk < 2; ++kk) {
            const float* p = qrow + kk * 32 + quad * 8;
            float4 a = *(const float4*)p;
            float4 c = *(const float4*)(p + 4);
            float f[8] = {a.x, a.y, a.z, a.w, c.x, c.y, c.z, c.w};
            bf16x8 hi, lo;
            #pragma unroll
            for (int j = 0; j < 8; ++j) {
                float fs = f[j] * LOG2E;
                __bf16 hj = (__bf16)fs;
                hi[j] = hj;
                lo[j] = (__bf16)(fs - (float)hj);
            }
            qhi[g][kk] = hi; qlo[g][kk] = lo;
        }
    }

    f32x4 oacc[2][4];             // [qset][cd] O^T accumulators (row'=d, col'=q)
    float ls[2] = {0.f, 0.f};     // per-lane partial row sums, per qset
    #pragma unroll
    for (int g = 0; g < 2; ++g)
        #pragma unroll
        for (int cd = 0; cd < 4; ++cd)
            oacc[g][cd] = (f32x4){0.f, 0.f, 0.f, 0.f};

    const size_t kbase = ((size_t)b * S) * (H * E) + (size_t)h * E;
    const size_t vbase = ((size_t)b * S) * (H * D) + (size_t)h * D;

    // K staging geometry: thread owns rows ks and ks+32, float4 kc4
    const int ks  = tid >> 4;           // 0..31
    const int kc4 = tid & 15;           // float4 index within row

    // V staging geometry: thread owns 1 d-row x 8 s (s = vsg*8 + t)
    const int vd  = tid & 63;           // d row
    const int vsg = tid >> 6;           // s-group (8 s each), 0..7
    // permuted slot base (slot E bits from s bits: E5=s5,E4=s3,E3=s2,E2=s4,E1=s1,E0=s0)
    const int VB0 = 32 * (vsg >> 2) + 16 * (vsg & 1) + 4 * ((vsg >> 1) & 1);

    float4 kr0, kr1;    // staged K (fp32, pre-convert)
    float  vr[8];       // staged V column

    // ---- issue global loads for tile st into registers (plain C loads;
    //      caller pins them with sched_barrier(0) so they cannot sink)
    auto issue_loads = [&](int st) {
        const int s0 = st * BN;
        kr0 = *(const float4*)(Kg + kbase + (size_t)(s0 + ks)      * (H * E) + kc4 * 4);
        kr1 = *(const float4*)(Kg + kbase + (size_t)(s0 + 32 + ks) * (H * E) + kc4 * 4);
        const float* vp = Vg + vbase + (size_t)(s0 + vsg * 8) * (H * D) + vd;
        #pragma unroll
        for (int j = 0; j < 8; ++j)
            vr[j] = vp[(size_t)j * (H * D)];
    };

    // ---- convert staged registers to bf16 and write LDS buffer buf
    // (identical conversion arithmetic to round 7)
    auto write_tile = [&](int buf) {
        bf16x4 h0, h1;
        h0[0] = (__bf16)kr0.x; h0[1] = (__bf16)kr0.y;
        h0[2] = (__bf16)kr0.z; h0[3] = (__bf16)kr0.w;
        h1[0] = (__bf16)kr1.x; h1[1] = (__bf16)kr1.y;
        h1[2] = (__bf16)kr1.z; h1[3] = (__bf16)kr1.w;
        *(bf16x4*)&Khi[buf][ks        * KP + kc4 * 4] = h0;
        *(bf16x4*)&Khi[buf][(32 + ks) * KP + kc4 * 4] = h1;
        bf16x4 lo4, hi4;
        #pragma unroll
        for (int j = 0; j < 4; ++j) {
            lo4[j] = (__bf16)vr[j];
            hi4[j] = (__bf16)vr[4 + j];
        }
        *(bf16x4*)&Vt[buf][vd * KP + VB0]     = lo4;
        *(bf16x4*)&Vt[buf][vd * KP + VB0 + 8] = hi4;
    };

    // ---- prologue: stage tile 0 synchronously
    issue_loads(0);
    write_tile(0);
    __syncthreads();

    for (int st = 0; st < NT; ++st) {
        const int cur = st & 1;

        // fire next tile's loads; pin them here so they can't sink to use site
        if (st + 1 < NT) {
            issue_loads(st + 1);
            __builtin_amdgcn_sched_barrier(0);
        }

        // ---- K fragments: 8 b128 reads, reused across both qsets
        bf16x8 kh[4][2];
        #pragma unroll
        for (int c = 0; c < 4; ++c)
            #pragma unroll
            for (int kk = 0; kk < 2; ++kk)
                kh[c][kk] = *(bf16x8*)&Khi[cur][(c * 16 + l16) * KP + kk * 32 + quad * 8];

        // ---- per qset: S^T = K·Q^T (2-term), exp2, pb built in-register
        bf16x8 pb[2][2];   // slot (quad,j) holds s = 16*(2kk+(j>>2)) + 4*quad + (j&3)
        #pragma unroll
        for (int g = 0; g < 2; ++g) {
            f32x4 sc[4];
            #pragma unroll
            for (int c = 0; c < 4; ++c) {
                f32x4 acc = (f32x4){0.f, 0.f, 0.f, 0.f};
                #pragma unroll
                for (int kk = 0; kk < 2; ++kk) {
                    acc = mfma16(kh[c][kk], qhi[g][kk], acc);
                    acc = mfma16(kh[c][kk], qlo[g][kk], acc);
                }
                sc[c] = acc;
            }
            float lg = 0.f;
            float pv[4][4];
            #pragma unroll
            for (int c = 0; c < 4; ++c)
                #pragma unroll
                for (int r = 0; r < 4; ++r) {
                    float p = EXP2F(sc[c][r]);
                    lg += p;
                    pv[c][r] = p;
                }
            ls[g] += lg;
            #pragma unroll
            for (int kk = 0; kk < 2; ++kk) {
                bf16x8 w;
                #pragma unroll
                for (int j = 0; j < 8; ++j)
                    w[j] = (__bf16)pv[2 * kk + (j >> 2)][j & 3];
                pb[g][kk] = w;
            }
        }

        // ---- O^T += V^T · P^T : V frags read once, reused across qsets
        #pragma unroll
        for (int cd = 0; cd < 4; ++cd) {
            #pragma unroll
            for (int kk = 0; kk < 2; ++kk) {
                bf16x8 va = *(bf16x8*)&Vt[cur][(cd * 16 + l16) * KP + kk * 32 + quad * 8];
                #pragma unroll
                for (int g = 0; g < 2; ++g)
                    oacc[g][cd] = mfma16(va, pb[g][kk], oacc[g][cd]);
            }
        }

        // ---- write next tile into the other buffer (compiler inserts the
        //      vmcnt wait for the staged loads right here, at first use)
        if (st + 1 < NT) write_tile(cur ^ 1);
        __syncthreads();   // publishes buf^1 writes, closes WAR on buf
    }

    // ---- epilogue: reduce row sums across quads, normalize, store O^T
    #pragma unroll
    for (int g = 0; g < 2; ++g) {
        float t = ls[g];
        t += __shfl_xor(t, 16);
        t += __shfl_xor(t, 32);
        float rl = 1.0f / t;
        const int q = q0w + g * 16 + l16;
        float* orow = Og + (((size_t)b * L + q) * H + h) * D;
        #pragma unroll
        for (int cd = 0; cd < 4; ++cd) {
            float4 v;
            v.x = oacc[g][cd][0] * rl;
            v.y = oacc[g][cd][1] * rl;
            v.z = oacc[g][cd][2] * rl;
            v.w = oacc[g][cd][3] * rl;
            *(float4*)(orow + cd * 16 + quad * 4) = v;
        }
    }
}

extern "C" void kernel_launch(void* const* d_in, const int* in_sizes, int n_in,
                              void* d_out, int out_size, void* d_ws, size_t ws_size,
                              hipStream_t stream) {
    const float* Q = (const float*)d_in[0];
    const float* K = (const float*)d_in[1];
    const float* V = (const float*)d_in[2];
    float* O = (float*)d_out;
    dim3 grid(4 * 16 * (2048 / BM));   // B*H*(L/BM) = 512 blocks
    dim3 block(512);
    hipLaunchKernelGGL(attn_kernel, grid, block, 0, stream, Q, K, V, O);
}

// Round 9
// 208.522 us; speedup vs baseline: 1.2157x; 1.2157x over previous
//
#include <hip/hip_runtime.h>
#include <hip/hip_bf16.h>

// Full attention, B=4 L=S=2048 H=16 E=D=64, fp32 in/out, UNSCALED scores.
// Round 13: round-7 structure EXACTLY (synchronous fused stage, 2 barriers,
// single-buffered LDS — verified 121 µs hot) + XCD sibling remap ONLY.
// Round-12 decomposition: remap = WIN (FETCH 278->57 MB, K/V reuse L2-local);
// prefetch pipeline = LOSS (sched_barrier(0) in hot loop defeated compiler
// scheduling, MfmaUtil 35->25%, the m141 regression mode). So: keep remap,
// drop pipeline. Stage latency is now L2-class instead of HBM-class, which
// directly shrinks the exposed stage stall the 2-barrier structure pays.
// Arithmetic per q-row bitwise-identical to round 7 (absmax 0.1015625):
// 2-term Q hi/lo split, bf16 K/P/V, fixed-max softmax via exp2(log2e*Q),
// in-register P^T with permuted V^T slot order.

#define BN 64    // S-tile
#define BM 256   // Q-tile per block (32 per wave, 2 qsets of 16)
#define KP 72    // padded LDS row stride (bf16 elems); 144 B = 9 bank-groups == 1 mod 8

typedef __attribute__((ext_vector_type(8))) __bf16 bf16x8;
typedef __attribute__((ext_vector_type(4))) __bf16 bf16x4;
typedef __attribute__((ext_vector_type(4))) float  f32x4;

#if __has_builtin(__builtin_amdgcn_exp2f)
#define EXP2F(x) __builtin_amdgcn_exp2f(x)
#else
#define EXP2F(x) exp2f(x)
#endif

__device__ __forceinline__ f32x4 mfma16(bf16x8 a, bf16x8 b, f32x4 c) {
    return __builtin_amdgcn_mfma_f32_16x16x32_bf16(a, b, c, 0, 0, 0);
}

__global__ __launch_bounds__(512, 4)
void attn_kernel(const float* __restrict__ Qg, const float* __restrict__ Kg,
                 const float* __restrict__ Vg, float* __restrict__ Og)
{
    constexpr int B = 4, L = 2048, S = 2048, H = 16, E = 64, D = 64;
    constexpr float LOG2E = 1.44269504088896f;

    __shared__ __bf16 Khi[BN * KP];     // K tile, bf16, [s][e]
    __shared__ __bf16 Vt [D  * KP];     // V^T [d][slot], slot = perm(s)

    const int tid  = threadIdx.x;
    const int lane = tid & 63;
    const int wv   = tid >> 6;          // 0..7
    const int quad = lane >> 4;
    const int l16  = lane & 15;

    // XCD sibling grouping: blk = qt*64 + bh -> the 8 qt-siblings of one bh
    // share blk%8 (same XCD under round-robin) -> K/V tile reuse is L2-local.
    // Measured round 12: FETCH 278 MB -> 57 MB.
    const int blk = blockIdx.x;
    const int qt  = blk >> 6;        // 0..7
    const int bh  = blk & 63;
    const int h   = bh & 15;
    const int b   = bh >> 4;

    const int q0w = qt * BM + wv * 32;   // this wave's first query row (32 rows)

    // ---- Load Q fragments once, scaled by log2(e), hi/lo split (residual in qlo)
    bf16x8 qhi[2][2], qlo[2][2];   // [qset][kk]
    #pragma unroll
    for (int g = 0; g < 2; ++g) {
        const float* qrow = Qg + (((size_t)b * L + q0w + g * 16 + l16) * H + h) * E;
        #pragma unroll
        for (int kk = 0; kk < 2; ++kk) {
            const float* p = qrow + kk * 32 + quad * 8;
            float4 a = *(const float4*)p;
            float4 c = *(const float4*)(p + 4);
            float f[8] = {a.x, a.y, a.z, a.w, c.x, c.y, c.z, c.w};
            bf16x8 hi, lo;
            #pragma unroll
            for (int j = 0; j < 8; ++j) {
                float fs = f[j] * LOG2E;
                __bf16 hj = (__bf16)fs;
                hi[j] = hj;
                lo[j] = (__bf16)(fs - (float)hj);
            }
            qhi[g][kk] = hi; qlo[g][kk] = lo;
        }
    }

    f32x4 oacc[2][4];             // [qset][cd] O^T accumulators (row'=d, col'=q)
    float ls[2] = {0.f, 0.f};     // per-lane partial row sums, per qset
    #pragma unroll
    for (int g = 0; g < 2; ++g)
        #pragma unroll
        for (int cd = 0; cd < 4; ++cd)
            oacc[g][cd] = (f32x4){0.f, 0.f, 0.f, 0.f};

    const size_t kbase = ((size_t)b * S) * (H * E) + (size_t)h * E;
    const size_t vbase = ((size_t)b * S) * (H * D) + (size_t)h * D;

    // V staging geometry: thread owns 1 d-row x 8 s (s = vsg*8 + t, t=0..7)
    const int vd  = tid & 63;           // d row
    const int vsg = tid >> 6;           // s-group (8 s each), 0..7
    // permuted slot base (slot E bits from s bits: E5=s5,E4=s3,E3=s2,E2=s4,E1=s1,E0=s0)
    const int VB0 = 32 * (vsg >> 2) + 16 * (vsg & 1) + 4 * ((vsg >> 1) & 1);

    for (int st = 0; st < S / BN; ++st) {
        const int s0 = st * BN;

        __syncthreads();   // WAR: prior iter's K/Vt reads done before overwrite

        // ---- stage K tile (bf16): 1024 float4 chunks, 2/thread, b64 LDS writes
        #pragma unroll
        for (int i = 0; i < 2; ++i) {
            int lin = tid + i * 512;      // 0..1023
            int s   = lin >> 4;           // 0..63
            int c4  = lin & 15;           // float4 index within row
            const float* p = Kg + kbase + (size_t)(s0 + s) * (H * E) + c4 * 4;
            float4 kq = *(const float4*)p;
            bf16x4 hi;
            hi[0] = (__bf16)kq.x; hi[1] = (__bf16)kq.y;
            hi[2] = (__bf16)kq.z; hi[3] = (__bf16)kq.w;
            *(bf16x4*)&Khi[s * KP + c4 * 4] = hi;
        }

        // ---- stage V^T in permuted s-order: coalesced reads, 2 b64 writes/thread
        {
            const float* vp = Vg + vbase + (size_t)(s0 + vsg * 8) * (H * D) + vd;
            float ra[8];
            #pragma unroll
            for (int j = 0; j < 8; ++j)
                ra[j] = vp[(size_t)j * (H * D)];
            bf16x4 lo4, hi4;
            #pragma unroll
            for (int j = 0; j < 4; ++j) {
                lo4[j] = (__bf16)ra[j];
                hi4[j] = (__bf16)ra[4 + j];
            }
            *(bf16x4*)&Vt[vd * KP + VB0]     = lo4;
            *(bf16x4*)&Vt[vd * KP + VB0 + 8] = hi4;
        }
        __syncthreads();

        // ---- K fragments: 8 b128 reads, reused across both qsets
        bf16x8 kh[4][2];
        #pragma unroll
        for (int c = 0; c < 4; ++c)
            #pragma unroll
            for (int kk = 0; kk < 2; ++kk)
                kh[c][kk] = *(bf16x8*)&Khi[(c * 16 + l16) * KP + kk * 32 + quad * 8];

        // ---- per qset: S^T = K·Q^T (2-term), exp2, pb built in-register
        bf16x8 pb[2][2];   // slot (quad,j) holds s = 16*(2kk+(j>>2)) + 4*quad + (j&3)
        #pragma unroll
        for (int g = 0; g < 2; ++g) {
            f32x4 sc[4];
            #pragma unroll
            for (int c = 0; c < 4; ++c) {
                f32x4 acc = (f32x4){0.f, 0.f, 0.f, 0.f};
                #pragma unroll
                for (int kk = 0; kk < 2; ++kk) {
                    acc = mfma16(kh[c][kk], qhi[g][kk], acc);
                    acc = mfma16(kh[c][kk], qlo[g][kk], acc);
                }
                sc[c] = acc;
            }
            float lg = 0.f;
            float pv[4][4];
            #pragma unroll
            for (int c = 0; c < 4; ++c)
                #pragma unroll
                for (int r = 0; r < 4; ++r) {
                    float p = EXP2F(sc[c][r]);
                    lg += p;
                    pv[c][r] = p;
                }
            ls[g] += lg;
            #pragma unroll
            for (int kk = 0; kk < 2; ++kk) {
                bf16x8 w;
                #pragma unroll
                for (int j = 0; j < 8; ++j)
                    w[j] = (__bf16)pv[2 * kk + (j >> 2)][j & 3];
                pb[g][kk] = w;
            }
        }

        // ---- O^T += V^T · P^T : V frags read once (plain layout), reused across qsets
        #pragma unroll
        for (int cd = 0; cd < 4; ++cd) {
            #pragma unroll
            for (int kk = 0; kk < 2; ++kk) {
                bf16x8 va = *(bf16x8*)&Vt[(cd * 16 + l16) * KP + kk * 32 + quad * 8];
                #pragma unroll
                for (int g = 0; g < 2; ++g)
                    oacc[g][cd] = mfma16(va, pb[g][kk], oacc[g][cd]);
            }
        }
    }

    // ---- epilogue: reduce row sums across quads, normalize, store O^T
    #pragma unroll
    for (int g = 0; g < 2; ++g) {
        float t = ls[g];
        t += __shfl_xor(t, 16);
        t += __shfl_xor(t, 32);
        float rl = 1.0f / t;
        const int q = q0w + g * 16 + l16;
        float* orow = Og + (((size_t)b * L + q) * H + h) * D;
        #pragma unroll
        for (int cd = 0; cd < 4; ++cd) {
            float4 v;
            v.x = oacc[g][cd][0] * rl;
            v.y = oacc[g][cd][1] * rl;
            v.z = oacc[g][cd][2] * rl;
            v.w = oacc[g][cd][3] * rl;
            *(float4*)(orow + cd * 16 + quad * 4) = v;
        }
    }
}

extern "C" void kernel_launch(void* const* d_in, const int* in_sizes, int n_in,
                              void* d_out, int out_size, void* d_ws, size_t ws_size,
                              hipStream_t stream) {
    const float* Q = (const float*)d_in[0];
    const float* K = (const float*)d_in[1];
    const float* V = (const float*)d_in[2];
    float* O = (float*)d_out;
    dim3 grid(4 * 16 * (2048 / BM));   // B*H*(L/BM) = 512 blocks
    dim3 block(512);
    hipLaunchKernelGGL(attn_kernel, grid, block, 0, stream, Q, K, V, O);
}